// Round 5
// baseline (182.283 us; speedup 1.0000x reference)
//
#include <hip/hip_runtime.h>
#include <hip/hip_bf16.h>
#include <stdint.h>

typedef unsigned short u16;
typedef unsigned int u32;
typedef __bf16 bf16x8 __attribute__((ext_vector_type(8)));
typedef _Float16 f16x8 __attribute__((ext_vector_type(8)));
typedef float f32x4 __attribute__((ext_vector_type(4)));

#define LOG2E 1.4426950408889634f

__device__ __forceinline__ u16 f2bf(float f) {
  u32 u = __builtin_bit_cast(u32, f);
  u += 0x7FFFu + ((u >> 16) & 1u);
  return (u16)(u >> 16);
}

__device__ __forceinline__ void gload_lds16(const void* g, void* l) {
  __builtin_amdgcn_global_load_lds(
      (const __attribute__((address_space(1))) u32*)g,
      (__attribute__((address_space(3))) u32*)l, 16, 0, 0);
}

// ---------------- convert / concat ----------------
__global__ void k_concat_bf16(const float* __restrict__ x, const float* __restrict__ y,
                              u16* __restrict__ xyb) {
  int tid = blockIdx.x * blockDim.x + threadIdx.x;
  int e = tid * 4;
  int s = e >> 9;
  int d = e & 511;
  int b = s >> 11, r = s & 2047;
  const float* src = (r < 1024) ? (x + ((size_t)(b * 1024 + r) * 512 + d))
                                : (y + ((size_t)(b * 1024 + (r - 1024)) * 512 + d));
  float4 v = *(const float4*)src;
  ushort4 o;
  o.x = f2bf(v.x); o.y = f2bf(v.y); o.z = f2bf(v.z); o.w = f2bf(v.w);
  *(ushort4*)(xyb + e) = o;
}

// all three weight matrices in one launch: Wq,Wk -> Wqkb (stacked), Wv -> Wvb
__global__ void k_w_to_bf16(const float* __restrict__ Wq, const float* __restrict__ Wk,
                            const float* __restrict__ Wv,
                            u16* __restrict__ Wqkb, u16* __restrict__ Wvb) {
  int tid = blockIdx.x * blockDim.x + threadIdx.x;  // 196608 threads
  int which = tid >> 16;
  int e = (tid & 65535) * 4;
  const float* src = (which == 0) ? Wq : (which == 1) ? Wk : Wv;
  u16* dst = (which == 0) ? Wqkb : (which == 1) ? (Wqkb + 262144) : Wvb;
  float4 v = *(const float4*)(src + e);
  ushort4 o;
  o.x = f2bf(v.x); o.y = f2bf(v.y); o.z = f2bf(v.z); o.w = f2bf(v.w);
  *(ushort4*)(dst + e) = o;
}

// ---------------- 256x128 triple-buffered GEMM: C = scale * A * B^T ----------------
// BM=256, BN=128, BK=64, 8 waves (4x2), wave tile 64x64, M_rep=4, N_rep=4.
// LDS: 3 buffers x (A 32KB + B 16KB) = 144KB. Rows are 128B, XOR-swizzled:
// storage(row, cb) = row*128 + (cb ^ ((row&7)<<4)); staged via pre-swizzled
// global source so global_load_lds dest stays linear.
// Schedule: stage tile kt+2 at top of tile kt; at tile end s_waitcnt vmcnt(6)
// (keeps kt+2's 6 loads in flight) + RAW s_barrier (no implicit drain).
// A: [z][M][K] stride lda, batch elem-offset sA; B likewise; C [z][M][N].
// OUTM: 0=bf16, 1=f16, 2=f32. ABF16: inputs are f16 (else bf16).
template <int ABF16, int OUTM>
__global__ __launch_bounds__(512, 2) void k_gemm256(
    const u16* __restrict__ A, const u16* __restrict__ B, void* __restrict__ Cv,
    int lda, int ldb, int ldc,
    long long sA, long long sB, long long sC,
    int K, float scale, int mtiles, int ntiles) {
  constexpr int A_BYTES = 256 * 128;  // 32 KB
  constexpr int B_BYTES = 128 * 128;  // 16 KB
  constexpr int BUFB = A_BYTES + B_BYTES;  // 48 KB

  __shared__ __align__(16) char lds[3 * BUFB];  // 144 KB

  int t = threadIdx.x;
  int lane = t & 63;
  int w = t >> 6;
  int wr = w >> 1, wc = w & 1;

  int bid = blockIdx.x;
  int ty = bid % ntiles;
  int r2 = bid / ntiles;
  int tx = r2 % mtiles;
  long long z = r2 / mtiles;

  size_t rsA = (size_t)lda * 2, rsB = (size_t)ldb * 2;
  int srow = t >> 3;
  int scb = ((t & 7) * 16) ^ ((srow & 7) << 4);  // pre-swizzled source byte col

  const char* Abt = (const char*)(A + z * sA + (size_t)tx * 256 * lda) + (size_t)srow * rsA + scb;
  const char* Bbt = (const char*)(B + z * sB + (size_t)ty * 128 * ldb) + (size_t)srow * rsB + scb;
  size_t rsA64 = rsA * 64, rsB64 = rsB * 64;
  int dstoff = t * 16;

  auto stage = [&](int buf, int kt) {
    char* dst = lds + buf * BUFB + dstoff;
    size_t kadv = (size_t)kt * 128;
#pragma unroll
    for (int r = 0; r < 4; ++r)
      gload_lds16(Abt + r * rsA64 + kadv, dst + r * 8192);
#pragma unroll
    for (int r = 0; r < 2; ++r)
      gload_lds16(Bbt + r * rsB64 + kadv, dst + A_BYTES + r * 8192);
  };

  // per-thread read offsets
  int axor = (lane & 7) << 4;
  int arow0 = wr * 64 + (lane & 15);
  int brow0 = wc * 64 + (lane & 15);
  int kb0 = (lane >> 4) * 16;

  f32x4 acc[4][4] = {};
  int NT = K >> 6;

  // prologue: stage tiles 0 and 1
  stage(0, 0);
  stage(1, 1);
  asm volatile("s_waitcnt vmcnt(6)" ::: "memory");  // tile 0 landed, tile 1 in flight
  __builtin_amdgcn_sched_barrier(0);
  __builtin_amdgcn_s_barrier();
  __builtin_amdgcn_sched_barrier(0);

  int bc = 0;  // buffer holding tile kt
  for (int kt = 0; kt < NT; ++kt) {
    const char* Abase = lds + bc * BUFB;
    const char* Bbase = Abase + A_BYTES;

    // fragment reads for this tile
    bf16x8 afr[4][2], bfr[4][2];
#pragma unroll
    for (int i = 0; i < 4; ++i)
#pragma unroll
      for (int kk = 0; kk < 2; ++kk) {
        afr[i][kk] = *(const bf16x8*)(Abase + (arow0 + i * 16) * 128 + ((kb0 + kk * 64) ^ axor));
        bfr[i][kk] = *(const bf16x8*)(Bbase + (brow0 + i * 16) * 128 + ((kb0 + kk * 64) ^ axor));
      }

    // stage tile kt+2 (two tiles ahead) into the buffer freed at last barrier
    if (kt + 2 < NT) {
      int bs = bc - 1; if (bs < 0) bs += 3;
      stage(bs, kt + 2);
    }
    __builtin_amdgcn_sched_barrier(0);

    __builtin_amdgcn_s_setprio(1);
#pragma unroll
    for (int i = 0; i < 4; ++i)
#pragma unroll
      for (int j = 0; j < 4; ++j)
#pragma unroll
        for (int kk = 0; kk < 2; ++kk) {
          if constexpr (ABF16) {
            acc[i][j] = __builtin_amdgcn_mfma_f32_16x16x32_f16(
                __builtin_bit_cast(f16x8, afr[i][kk]), __builtin_bit_cast(f16x8, bfr[j][kk]),
                acc[i][j], 0, 0, 0);
          } else {
            acc[i][j] = __builtin_amdgcn_mfma_f32_16x16x32_bf16(
                afr[i][kk], bfr[j][kk], acc[i][j], 0, 0, 0);
          }
        }
    __builtin_amdgcn_s_setprio(0);
    __builtin_amdgcn_sched_barrier(0);

    if (kt + 1 < NT) {
      // wait for tile kt+1 only; tile kt+2's 6 loads stay in flight
      if (kt + 2 < NT) asm volatile("s_waitcnt vmcnt(6)" ::: "memory");
      else             asm volatile("s_waitcnt vmcnt(0)" ::: "memory");
      __builtin_amdgcn_sched_barrier(0);
      __builtin_amdgcn_s_barrier();
      __builtin_amdgcn_sched_barrier(0);
    }
    bc = (bc + 1 == 3) ? 0 : bc + 1;
  }

  // epilogue
#pragma unroll
  for (int m = 0; m < 4; ++m) {
    int row = tx * 256 + wr * 64 + m * 16 + ((lane >> 4) << 2);
#pragma unroll
    for (int n = 0; n < 4; ++n) {
      int col = ty * 128 + wc * 64 + n * 16 + (lane & 15);
#pragma unroll
      for (int r = 0; r < 4; ++r) {
        float v = acc[m][n][r] * scale;
        size_t idx = (size_t)(z * sC) + (size_t)(row + r) * ldc + col;
        if constexpr (OUTM == 0) ((u16*)Cv)[idx] = f2bf(v);
        else if constexpr (OUTM == 1) ((_Float16*)Cv)[idx] = (_Float16)v;
        else ((float*)Cv)[idx] = v;
      }
    }
  }
}

// ---------------- row softmax, f16 in-place, rows of 2048 ----------------
__global__ __launch_bounds__(256) void k_softmax_f16(_Float16* __restrict__ S) {
  int row = blockIdx.x * 4 + (threadIdx.x >> 6);
  int lane = threadIdx.x & 63;
  _Float16* Sr = S + (size_t)row * 2048;

  f16x8 v[4];
#pragma unroll
  for (int i = 0; i < 4; ++i) v[i] = *(const f16x8*)(Sr + i * 512 + lane * 8);

  float f[32];
#pragma unroll
  for (int i = 0; i < 4; ++i)
#pragma unroll
    for (int j = 0; j < 8; ++j) f[i * 8 + j] = (float)v[i][j];

  float mx = f[0];
#pragma unroll
  for (int i = 1; i < 32; ++i) mx = fmaxf(mx, f[i]);
#pragma unroll
  for (int off = 1; off < 64; off <<= 1) mx = fmaxf(mx, __shfl_xor(mx, off));

  float sum = 0.0f;
#pragma unroll
  for (int i = 0; i < 32; ++i) {
    f[i] = exp2f((f[i] - mx) * LOG2E);
    sum += f[i];
  }
#pragma unroll
  for (int off = 1; off < 64; off <<= 1) sum += __shfl_xor(sum, off);

  float inv = 1.0f / sum;
  f16x8 o[4];
#pragma unroll
  for (int i = 0; i < 4; ++i)
#pragma unroll
    for (int j = 0; j < 8; ++j) o[i][j] = (_Float16)(f[i * 8 + j] * inv);
#pragma unroll
  for (int i = 0; i < 4; ++i) *(f16x8*)(Sr + i * 512 + lane * 8) = o[i];
}

extern "C" void kernel_launch(void* const* d_in, const int* in_sizes, int n_in,
                              void* d_out, int out_size, void* d_ws, size_t ws_size,
                              hipStream_t stream) {
  const float* x = (const float*)d_in[0];
  const float* y = (const float*)d_in[1];
  const float* Wq = (const float*)d_in[2];
  const float* Wk = (const float*)d_in[3];
  const float* Wv = (const float*)d_in[4];
  float* out = (float*)d_out;

  char* p = (char*)d_ws;
  u16* QKb = (u16*)p; p += (size_t)16384 * 1024 * 2;  // Q cols 0-511, K cols 512-1023 (bf16)
  u16* VTh = (u16*)p; p += (size_t)16384 * 512 * 2;   // f16 payload [512][16384]
  u16* Wqkb = (u16*)p; p += (size_t)1024 * 512 * 2;   // [Wq;Wk]
  u16* Wvb = (u16*)p; p += (size_t)512 * 512 * 2;
  size_t base = (size_t)(p - (char*)d_ws);
  u16* xyb = (u16*)p;          // dead after VT projection
  _Float16* Sb = (_Float16*)p; // aliases xyb

  int nc = (ws_size >= base + (size_t)16384 * 2048 * 2) ? 1 : 2;
  int mrows = 2048 / nc;
  int mt = mrows / 256;

  // converts
  k_concat_bf16<<<8192, 256, 0, stream>>>(x, y, xyb);
  k_w_to_bf16<<<768, 256, 0, stream>>>(Wq, Wk, Wv, Wqkb, Wvb);

  // fused Q/K projection: [16384][1024] = xy @ [Wq;Wk]^T  (bf16 out)  grid 64x8
  k_gemm256<0, 0><<<512, 512, 0, stream>>>(
      xyb, Wqkb, QKb, 512, 512, 1024, 0, 0, 0, 512, 1.0f, 64, 8);
  // VT projection: [512][16384] = Wv @ xy^T  (f16 out)  grid 2x128
  k_gemm256<0, 1><<<256, 512, 0, stream>>>(
      Wvb, xyb, VTh, 512, 512, 16384, 0, 0, 0, 512, 1.0f, 2, 128);

  const float scale = 0.044194173824159216f;  // 1/sqrt(512)
  for (int c = 0; c < nc; ++c) {
    const u16* Qc = QKb + (size_t)c * mrows * 1024;
    // S = scale * Q K^T  (f16 out): per-batch [mrows][2048]  grid z=8, mt x 16
    k_gemm256<0, 1><<<8 * mt * 16, 512, 0, stream>>>(
        Qc, QKb + 512, Sb, 1024, 1024, 2048,
        (long long)2048 * 1024, (long long)2048 * 1024, (long long)mrows * 2048,
        512, scale, mt, 16);
    // softmax in place
    k_softmax_f16<<<(8 * mrows) / 4, 256, 0, stream>>>(Sb);
    // O = P @ VT^T (f16 in, f32 out)  grid z=8, mt x 4
    k_gemm256<1, 2><<<8 * mt * 4, 512, 0, stream>>>(
        (const u16*)Sb, VTh, out + (size_t)c * mrows * 512, 2048, 16384, 512,
        (long long)mrows * 2048, (long long)2048, (long long)2048 * 512,
        2048, 1.0f, mt, 4);
  }
}